// Round 1
// 612.623 us; speedup vs baseline: 1.0179x; 1.0179x over previous
//
#include <hip/hip_runtime.h>

// Horizon_AttentionPooling: block-diagonal attention.
// T=2048, NUM_SEG=64, SEG=32, F_DIM=32, H_DIM=128, FEAT_DIM=4.
// Off-segment entries are -inf before softmax -> only diagonal 32x32 blocks
// matter. seg_size==32>1 always -> final zeroing never applies.
//
// R1 change: Wh = h @ Ww^T + Wb precomputed ONCE in a 256-KB workspace by a
// tiny kernel (was recomputed 4x per segment with a 512-deep serial scalar
// FMA chain per thread). Main kernel stages Wh (4 KB) + h (16 KB) via float4
// and hoists all per-row global loads (f, features, hor) above the staging
// barrier so their HBM latency overlaps the LDS fill.

#define TT 2048
#define SEG 32
#define FD 32
#define HD 128

// ---------------- kernel 1: Wh[t][ff] = h[t,:] . Ww[ff,:] + Wb[ff] ---------
__global__ __launch_bounds__(256) void wh_kernel(
    const float* __restrict__ h, const float* __restrict__ Ww,
    const float* __restrict__ Wb, float* __restrict__ wh)
{
    const int t  = blockIdx.x * 8 + (threadIdx.x >> 5);  // 8 rows per block
    const int ff = threadIdx.x & 31;
    const float4* hrow = (const float4*)(h + (size_t)t * HD);   // broadcast in 32-lane group
    const float4* wrow = (const float4*)(Ww + (size_t)ff * HD); // per-lane row
    float acc = 0.f;
    #pragma unroll
    for (int q = 0; q < HD / 4; ++q) {
        const float4 a = hrow[q];
        const float4 b = wrow[q];
        acc += a.x * b.x + a.y * b.y + a.z * b.z + a.w * b.w;
    }
    wh[(size_t)t * FD + ff] = acc + Wb[ff];
}

// ---------------- kernel 2: block-diagonal attention ----------------------
__global__ __launch_bounds__(256) void horizon_attn_kernel(
    const float* __restrict__ f, const float* __restrict__ h,
    const float* __restrict__ features, const float* __restrict__ hor,
    const float* __restrict__ wh, float* __restrict__ out)
{
    __shared__ float sh_h[SEG][HD];          // 16 KB: h rows of this segment
    __shared__ float sh_Wh[SEG][FD + 4];     // +4 pad: rows 144 B (16B-aligned, banks spread)
    __shared__ float sh_attn[8][SEG];

    const int tid = threadIdx.x;
    const int seg = blockIdx.x >> 2;                        // 4 blocks per segment
    const int rowBase = seg * SEG + (blockIdx.x & 3) * 8;   // 8 rows per block
    const int j0 = seg * SEG;

    const int r  = tid >> 5;        // 0..7  (row within block)
    const int jj = tid & 31;        // 0..31 (col within segment)
    const int i  = rowBase + r;
    const int j  = j0 + jj;

    // ---- issue ALL independent global loads up front (overlap latency) ----
    // per-row f fragment: 128 B contiguous per (i,j)
    const float* frow = f + ((size_t)i * TT + j) * FD;
    float4 fv[8];
    #pragma unroll
    for (int k = 0; k < 8; ++k) fv[k] = *(const float4*)(frow + 4 * k);
    const float dist = features[((size_t)i * TT + j) * 4];  // features[...,0]
    const float hb   = hor[(size_t)i * TT + j];

    // ---- stage h[j0:j0+32,:] (1024 float4) and Wh segment (256 float4) ----
    {
        const float4* hseg = (const float4*)(h + (size_t)j0 * HD);
        float4* shh4 = (float4*)&sh_h[0][0];
        #pragma unroll
        for (int v = tid; v < (SEG * HD) / 4; v += 256) shh4[v] = hseg[v];

        const float4 wv = ((const float4*)(wh + (size_t)j0 * FD))[tid];
        const int wjj = tid >> 3, wkq = tid & 7;            // row, quad within row
        *(float4*)&sh_Wh[wjj][wkq * 4] = wv;
    }
    __syncthreads();

    // ---- logit + mask + 32-wide softmax ----
    float logit = 0.f;
    #pragma unroll
    for (int k = 0; k < FD; k += 4) {
        const float4 wq = *(const float4*)&sh_Wh[jj][k];
        const float4 fq = fv[k >> 2];
        logit += fq.x * wq.x + fq.y * wq.y + fq.z * wq.z + fq.w * wq.w;
    }

    const bool bad = (hb < 0.f) | (dist > 10.f) | (i == j);
    const float m = bad ? -1000.f : logit;

    // softmax over the 32 lanes of this row (masks <=16 stay in 32-lane half)
    float mx = m;
    #pragma unroll
    for (int mask = 16; mask; mask >>= 1) mx = fmaxf(mx, __shfl_xor(mx, mask));
    const float e = __expf(m - mx);
    float s = e;
    #pragma unroll
    for (int mask = 16; mask; mask >>= 1) s += __shfl_xor(s, mask);
    sh_attn[r][jj] = e / s;
    __syncthreads();

    // ---- S[i,:] = sum_q attn[q] * h[j0+q,:]; each thread does 4 dims ----
    const int d0 = jj * 4;
    float4 acc = make_float4(0.f, 0.f, 0.f, 0.f);
    #pragma unroll 8
    for (int q = 0; q < SEG; ++q) {
        const float a = sh_attn[r][q];
        const float4 hv = *(const float4*)&sh_h[q][d0];
        acc.x += a * hv.x; acc.y += a * hv.y;
        acc.z += a * hv.z; acc.w += a * hv.w;
    }
    *(float4*)(out + (size_t)i * HD + d0) = acc;
}

extern "C" void kernel_launch(void* const* d_in, const int* in_sizes, int n_in,
                              void* d_out, int out_size, void* d_ws, size_t ws_size,
                              hipStream_t stream) {
    const float* f        = (const float*)d_in[0];
    const float* h        = (const float*)d_in[1];
    const float* features = (const float*)d_in[2];
    const float* hor      = (const float*)d_in[3];
    const float* Ww       = (const float*)d_in[4];
    const float* Wb       = (const float*)d_in[5];
    // d_in[6] (sub_batches) encodes uniform 32-row segments; structure is
    // fixed by the problem constants, hardcoded above.
    float* out = (float*)d_out;
    float* wh  = (float*)d_ws;   // 2048*32*4 = 256 KB scratch

    hipLaunchKernelGGL(wh_kernel, dim3(TT / 8), dim3(256), 0, stream,
                       h, Ww, Wb, wh);
    hipLaunchKernelGGL(horizon_attn_kernel, dim3(256), dim3(256), 0, stream,
                       f, h, features, hor, wh, out);
}